// Round 9
// baseline (14542.281 us; speedup 1.0000x reference)
//
#include <hip/hip_runtime.h>
#include <hip/hip_cooperative_groups.h>

namespace cg = cooperative_groups;

typedef unsigned short ushort_t;
typedef __attribute__((ext_vector_type(8))) short bf16x8;
typedef __attribute__((ext_vector_type(4))) float f32x4;

#define B_    1024
#define H_    1024
#define FEAT_ 75
#define KP_   1120          // packed K: 1024 h + 75 x + 21 zero pad
#define NKT   35            // K-chunks of 32
#define NKH   18            // K-chunks per half (kh0: 0..17, kh1: 18..34)
#define SLOT  16384         // pair slot: 2 tiles x 8KB
#define OFF_CP 1920000UL    // 1024*25*75
#define OFF_CV 5760000UL    // OFF_CP + 1024*50*75

// LDS map: 3 pair-slots (49152) + 8 wave scratch areas (16x17 f32 = 1088B)
#define LDS_SCR 49152
#define LDS_TOT 57856

__device__ __forceinline__ float bf2f(ushort_t u) {
    unsigned x = ((unsigned)u) << 16;
    float f; __builtin_memcpy(&f, &x, 4); return f;
}
__device__ __forceinline__ ushort_t f2bf(float f) {
    unsigned x; __builtin_memcpy(&x, &f, 4);
    x += 0x7fffu + ((x >> 16) & 1u);          // RNE
    return (ushort_t)(x >> 16);
}
__device__ __forceinline__ float sigm(float x) { return 1.f / (1.f + __expf(-x)); }

__device__ __forceinline__ void gload16(const void* g, void* l) {
    __builtin_amdgcn_global_load_lds(
        (const __attribute__((address_space(1))) void*)g,
        (__attribute__((address_space(3))) void*)l, 16, 0, 0);
}

// ---------------------------------------------------------------------------
// Half-K W-fragments: wave owns 16 gate-cols (4 j x 4 gates) and ONE K-half.
// bw[18] = 72 VGPRs (vs 140 full-K) -> fits the 128-VGPR cap, no spill.
// ---------------------------------------------------------------------------
__device__ __forceinline__ void load_w_half(bf16x8 (&bw)[NKH],
                                            const ushort_t* __restrict__ Wt,
                                            int j0w, int l, int kh)
{
    const int c16 = l & 15;
    const size_t row = (size_t)((c16 >> 2) << 10) + (c16 & 3) + j0w;
    const ushort_t* p = Wt + row * KP_ + ((l >> 4) << 3) + kh * NKH * 32;
    const int n = kh ? 17 : 18;          // kh1 covers kt 18..34 (17 chunks)
    #pragma unroll
    for (int kt = 0; kt < NKH; ++kt) {
        if (kt < n) bw[kt] = *(const bf16x8*)(p + kt * 32);
        else        { bf16x8 z = {0,0,0,0,0,0,0,0}; bw[kt] = z; }
    }
}

// ---------------------------------------------------------------------------
// One M=128 GEMM pass + fused LSTM cell. B from registers (half-K per wave);
// A staged in kt-pairs {i, 18+i} via global_load_lds, 3-slot pipeline with
// counted vmcnt. Epilogue: all waves dump acc[m] to their scratch; the owner
// wave (kh == m>>2) sums the two K-half partials, applies the cell, writes h.
// ---------------------------------------------------------------------------
__device__ __forceinline__ void run_pass(
    char* lds, const ushort_t* __restrict__ Ain, ushort_t* __restrict__ Aout,
    const bf16x8 (&bw)[NKH], float (&cr)[4],
    float bsi, float bsf, float bsg, float bso,
    int R0, int jcol_base, int tid, int w, int l, int kh, int ws,
    int write_c, float* __restrict__ cglob)
{
    const int srow = tid >> 2;                       // 0..127
    const int csrc = (tid & 3) ^ (srow & 3);         // inv-swizzled src chunk
    const ushort_t* asrc = Ain + (size_t)(R0 + srow) * KP_ + (csrc << 3);
    const int adst = (w << 10);                      // wave stages rows w*16..
    const int abase = ((l & 15) << 6) + (((l >> 4) ^ (l & 3)) << 4);
    float* sc = (float*)(lds + LDS_SCR);

    f32x4 acc[8];
    #pragma unroll
    for (int m = 0; m < 8; ++m) acc[m] = (f32x4){0.f, 0.f, 0.f, 0.f};

    asm volatile("s_waitcnt vmcnt(0)" ::: "memory");  // pin vm counter base

    // prologue: pairs 0,1 -> slots 0,1 (2 gloads per pair per thread)
    #pragma unroll
    for (int j = 0; j < 2; ++j) {
        gload16(asrc + (size_t)j * 32,        lds + j * SLOT + adst);
        gload16(asrc + (size_t)(NKH + j) * 32, lds + j * SLOT + 8192 + adst);
    }

    #pragma unroll
    for (int i = 0; i < NKH; ++i) {
        if (i + 2 <= 17) {
            const int j = i + 2;
            const int s = j % 3;
            const int kb = (NKH + j <= 34) ? (NKH + j) : j;   // dummy at j=17
            gload16(asrc + (size_t)j * 32,  lds + s * SLOT + adst);
            gload16(asrc + (size_t)kb * 32, lds + s * SLOT + 8192 + adst);
            asm volatile("s_waitcnt vmcnt(4)" ::: "memory");
        } else if (i == 16) {
            asm volatile("s_waitcnt vmcnt(2)" ::: "memory");
        } else {
            asm volatile("s_waitcnt vmcnt(0)" ::: "memory");
        }
        __builtin_amdgcn_s_barrier();
        asm volatile("" ::: "memory");

        if (kh == 0 || i < 17) {          // kh1 has only 17 chunks
            const char* bp = lds + (i % 3) * SLOT + kh * 8192;
            __builtin_amdgcn_s_setprio(1);
            #pragma unroll
            for (int m = 0; m < 8; ++m) {
                const bf16x8 a = *(const bf16x8*)(bp + (m << 10) + abase);
                acc[m] = __builtin_amdgcn_mfma_f32_16x16x32_bf16(a, bw[i], acc[m], 0, 0, 0);
            }
            __builtin_amdgcn_s_setprio(0);
        }
        asm volatile("" ::: "memory");
        __builtin_amdgcn_s_barrier();
    }

    // ---- epilogue: cross-wave K-reduction + fused LSTM cell ----
    const int row2 = l >> 2, jj = l & 3;
    const int jcol = jcol_base + jj;
    float* scw = sc + w * 272;                 // own 16x17 area
    const float* s0 = sc + ws * 272;           // kh0 partial of the pair
    const float* s1 = sc + (ws + 4) * 272;     // kh1 partial
    #pragma unroll
    for (int m = 0; m < 8; ++m) {
        #pragma unroll
        for (int r = 0; r < 4; ++r)
            scw[(((l >> 4) << 2) + r) * 17 + (l & 15)] = acc[m][r];
        asm volatile("s_waitcnt lgkmcnt(0)" ::: "memory");  // writes visible
        __builtin_amdgcn_s_barrier();
        if ((m >> 2) == kh) {                  // owner wave for this m-tile
            const int mi = m & 3;
            const float gi = s0[row2 * 17 + jj]      + s1[row2 * 17 + jj];
            const float gf = s0[row2 * 17 + 4 + jj]  + s1[row2 * 17 + 4 + jj];
            const float gg = s0[row2 * 17 + 8 + jj]  + s1[row2 * 17 + 8 + jj];
            const float go = s0[row2 * 17 + 12 + jj] + s1[row2 * 17 + 12 + jj];
            const float cn = sigm(gf + bsf) * cr[mi] + sigm(gi + bsi) * tanhf(gg + bsg);
            cr[mi] = cn;
            const int grow = R0 + (m << 4) + row2;
            Aout[(size_t)grow * KP_ + jcol] = f2bf(sigm(go + bso) * tanhf(cn));
            if (write_c) cglob[((size_t)grow << 10) + jcol] = cn;
        }
        asm volatile("" ::: "memory");
        __builtin_amdgcn_s_barrier();
    }
}

// ---------------------------------------------------------------------------
// fc phase (decoder): 128 active blocks x 8 rows (4x fcW reuse vs 2-row).
// Fuses clip, comp_vel/comp_pose writes, cumsum, bf16 x-feedback.
// ---------------------------------------------------------------------------
__device__ __forceinline__ void fc_phase(
    char* lds, ushort_t* __restrict__ Ah,
    const ushort_t* __restrict__ fcWb, const float* __restrict__ fcb,
    float* __restrict__ accp, float* __restrict__ out,
    int d, int tid, int blk)
{
    if ((blk >> 3) >= 16) return;              // 128 active blocks
    float* hs = (float*)lds;                   // 8 x 1024 f32 (reuses stage area)
    const int r0 = (blk & 7) * 128 + (blk >> 3) * 8;
    {
        const int r  = tid >> 6;               // 0..7
        const int k16 = (tid & 63) << 4;
        const ushort_t* src = Ah + (size_t)(r0 + r) * KP_ + k16;
        const bf16x8 v0 = *(const bf16x8*)(src);
        const bf16x8 v1 = *(const bf16x8*)(src + 8);
        #pragma unroll
        for (int u = 0; u < 8; ++u) {
            hs[(r << 10) + k16 + u]     = bf2f((ushort_t)v0[u]);
            hs[(r << 10) + k16 + 8 + u] = bf2f((ushort_t)v1[u]);
        }
    }
    __syncthreads();
    const int r  = tid >> 6;
    const int fb = tid & 63;
    #pragma unroll
    for (int half = 0; half < 2; ++half) {
        const int f = half * 64 + fb;
        if (f < FEAT_) {
            const ushort_t* wr = fcWb + (size_t)f * 1024;
            const float* hr = hs + (r << 10);
            float s0 = fcb[f], s1 = 0.f, s2 = 0.f, s3 = 0.f;
            for (int k = 0; k < 1024; k += 32) {
                const bf16x8 w0 = *(const bf16x8*)(wr + k);
                const bf16x8 w1 = *(const bf16x8*)(wr + k + 8);
                const bf16x8 w2 = *(const bf16x8*)(wr + k + 16);
                const bf16x8 w3 = *(const bf16x8*)(wr + k + 24);
                #pragma unroll
                for (int u = 0; u < 8; ++u) {
                    s0 = fmaf(hr[k + u],      bf2f((ushort_t)w0[u]), s0);
                    s1 = fmaf(hr[k + 8 + u],  bf2f((ushort_t)w1[u]), s1);
                    s2 = fmaf(hr[k + 16 + u], bf2f((ushort_t)w2[u]), s2);
                    s3 = fmaf(hr[k + 24 + u], bf2f((ushort_t)w3[u]), s3);
                }
            }
            float s = (s0 + s1) + (s2 + s3);
            s = fminf(fmaxf(s, -1.f), 1.f);
            const int row = r0 + r;
            const float pnew = accp[row * FEAT_ + f] + s;
            accp[row * FEAT_ + f] = pnew;
            out[OFF_CV + ((size_t)row * 49 + d) * FEAT_ + f]     = s;
            out[OFF_CP + ((size_t)row * 50 + d + 1) * FEAT_ + f] = pnew;
            Ah[(size_t)row * KP_ + 1024 + f] = f2bf(s);
        }
    }
    __syncthreads();
}

// ---------------------------------------------------------------------------
struct MainArgs {
    ushort_t*       A[3][2];     // [pe,ve,dec][ping,pong] 1024 x KP_ bf16
    const ushort_t* W[3];        // packed 4096 x KP_ bf16
    const float*    bias[3];
    float*          c_pe; float* c_ve;
    const ushort_t* pose_bf; const ushort_t* vel_bf;
    const ushort_t* fcWb; const float* fcb;
    float*          accp; float* out;
};

// ---------------------------------------------------------------------------
// Persistent cooperative kernel: 512 blocks x 512 threads (2 blocks/CU,
// 16 waves/CU). launch_bounds(512,4): VGPR cap 128 -- the design fits it
// (bw 72 + acc 32 + ~25 misc), so no spill regardless of compiler mood.
// Encoder: blk -> p=blk&1, q=(blk>>1)&3, g5=blk>>3 (16 j-cols each);
// XCD blk&7 hosts one (p,q): per-step h flows stay on one L2.
// ---------------------------------------------------------------------------
__global__ __launch_bounds__(512, 4)
void main_kernel(MainArgs ma)
{
    cg::grid_group grid = cg::this_grid();
    __shared__ __align__(16) char lds[LDS_TOT];
    const int tid = threadIdx.x;
    const int w = tid >> 6, l = tid & 63;
    const int kh = w >> 2, ws = w & 3;      // K-half, j-slot
    const int blk = blockIdx.x;

    // encoder geometry
    const int p  = blk & 1;
    const int q  = (blk >> 1) & 3;
    const int g5 = blk >> 3;                // 0..63
    const int jb = (g5 << 4) + (ws << 2);   // wave's 4 j-cols

    bf16x8 bw[NKH];
    load_w_half(bw, ma.W[p], jb, l, kh);
    const int jl = jb + (l & 3);
    float bsi = ma.bias[p][jl];
    float bsf = ma.bias[p][1024 + jl];
    float bsg = ma.bias[p][2048 + jl];
    float bso = ma.bias[p][3072 + jl];

    float crA[4], crB[4];
    #pragma unroll
    for (int m = 0; m < 4; ++m) { crA[m] = 0.f; crB[m] = 0.f; }

    float* cglob = (p == 0) ? ma.c_pe : ma.c_ve;
    const int tlast = (p == 0) ? 49 : 48;

    // ---------------- encoders: 50 steps ----------------
    for (int t = 0; t < 50; ++t) {
        if (p == 0 || t < 49) {
            const ushort_t* Ain = ma.A[p][t & 1];
            ushort_t* Aout = ma.A[p][(t + 1) & 1];
            if (g5 == 0) {   // x_{t+1} copy for this (p,q)'s 256 rows
                const ushort_t* xn = nullptr; int xstr = 0;
                if (p == 0 && t < 49) { xn = ma.pose_bf + (size_t)(t + 1) * 75; xstr = 3750; }
                if (p == 1 && t < 48) { xn = ma.vel_bf  + (size_t)(t + 1) * 75; xstr = 3675; }
                if (xn) {
                    for (int i = tid; i < 256 * 75; i += 512) {
                        const int r = i / 75, f = i - r * 75;
                        Aout[(size_t)(q * 256 + r) * KP_ + 1024 + f] =
                            xn[(size_t)(q * 256 + r) * xstr + f];
                    }
                }
            }
            const int wc = (t == tlast);
            run_pass(lds, Ain, Aout, bw, crA, bsi, bsf, bsg, bso,
                     q * 256,       jb, tid, w, l, kh, ws, wc, cglob);
            run_pass(lds, Ain, Aout, bw, crB, bsi, bsf, bsg, bso,
                     q * 256 + 128, jb, tid, w, l, kh, ws, wc, cglob);
        }
        grid.sync();
    }

    // ---------------- combine (cross-XCD boundary; fenced) ----------------
    __threadfence();
    grid.sync();
    {
        const ushort_t* hpe = ma.A[0][0];   // pe final
        const ushort_t* hve = ma.A[1][1];   // ve final
        ushort_t* Ad = ma.A[2][0];
        for (int k = tid; k < 2048; k += 512) {
            const int idx = (blk << 11) + k;
            const size_t o = (size_t)(idx >> 10) * KP_ + (idx & 1023);
            Ad[o] = f2bf(bf2f(hpe[o]) + bf2f(hve[o]));
        }
    }
    __threadfence();
    grid.sync();

    // ---------------- decoder init: reload W-half, fold c_pe+c_ve ----------
    const int oct = blk & 7;
    const int g5d = blk >> 3;               // 0..63
    const int jbd = (g5d << 4) + (ws << 2);
    load_w_half(bw, ma.W[2], jbd, l, kh);
    {
        const int jd = jbd + (l & 3);
        bsi = ma.bias[2][jd];
        bsf = ma.bias[2][1024 + jd];
        bsg = ma.bias[2][2048 + jd];
        bso = ma.bias[2][3072 + jd];
        const int row2 = l >> 2, jj = l & 3;
        #pragma unroll
        for (int mi = 0; mi < 4; ++mi) {
            const int m = (kh << 2) + mi;   // this wave owns these m-tiles
            const size_t o = ((size_t)(oct * 128 + m * 16 + row2) << 10) + jbd + jj;
            crA[mi] = ma.c_pe[o] + ma.c_ve[o];
        }
    }

    // ---------------- decoder: 49 x (step ; fc) ----------------
    for (int d = 0; d < 49; ++d) {
        run_pass(lds, ma.A[2][d & 1], ma.A[2][(d + 1) & 1], bw, crA,
                 bsi, bsf, bsg, bso, oct * 128, jbd, tid, w, l, kh, ws, 0, nullptr);
        grid.sync();
        fc_phase(lds, ma.A[2][(d + 1) & 1], ma.fcWb, ma.fcb, ma.accp, ma.out, d, tid, blk);
        grid.sync();
    }
}

// ---------------------------------------------------------------------------
// Pack / prep (proven, unchanged).
// ---------------------------------------------------------------------------
__global__ __launch_bounds__(256)
void pack_kernel(const float* __restrict__ peWih, const float* __restrict__ peWhh,
                 const float* __restrict__ veWih, const float* __restrict__ veWhh,
                 const float* __restrict__ deWih, const float* __restrict__ deWhh,
                 const float* __restrict__ pe_bih, const float* __restrict__ pe_bhh,
                 const float* __restrict__ ve_bih, const float* __restrict__ ve_bhh,
                 const float* __restrict__ de_bih, const float* __restrict__ de_bhh,
                 const float* __restrict__ fcW,
                 ushort_t* __restrict__ Wp, float* __restrict__ biasp,
                 ushort_t* __restrict__ fcWb)
{
    const size_t PER = 4096UL * KP_;
    const size_t NW  = 3UL * PER;
    const size_t NB  = 3UL * 4096;
    const size_t NF  = 75UL * 1024;
    for (size_t idx = (size_t)blockIdx.x * blockDim.x + threadIdx.x;
         idx < NW + NB + NF; idx += (size_t)gridDim.x * blockDim.x) {
        if (idx < NW) {
            const int pp  = (int)(idx / PER);
            const size_t rem = idx % PER;
            const int row = (int)(rem / KP_);
            const int k   = (int)(rem % KP_);
            const float* Whh = (pp == 0) ? peWhh : (pp == 1) ? veWhh : deWhh;
            const float* Wih = (pp == 0) ? peWih : (pp == 1) ? veWih : deWih;
            float v = 0.f;
            if (k < 1024)      v = Whh[(size_t)row * 1024 + k];
            else if (k < 1099) v = Wih[(size_t)row * 75 + (k - 1024)];
            Wp[idx] = f2bf(v);
        } else if (idx < NW + NB) {
            const size_t i = idx - NW;
            const int pp = (int)(i / 4096);
            const int r = (int)(i % 4096);
            const float* bih = (pp == 0) ? pe_bih : (pp == 1) ? ve_bih : de_bih;
            const float* bhh = (pp == 0) ? pe_bhh : (pp == 1) ? ve_bhh : de_bhh;
            biasp[i] = bih[r] + bhh[r];
        } else {
            const size_t i = idx - NW - NB;
            fcWb[i] = f2bf(fcW[i]);
        }
    }
}

__global__ __launch_bounds__(256)
void prep_kernel(const float* __restrict__ pose, const float* __restrict__ fut,
                 const int* __restrict__ noise,
                 ushort_t* __restrict__ pose_bf, ushort_t* __restrict__ vel_bf,
                 ushort_t* __restrict__ A_pe0, ushort_t* __restrict__ A_ve0,
                 ushort_t* __restrict__ A_dec0,
                 float* __restrict__ accp, float* __restrict__ out)
{
    const size_t N0 = 1024UL * 50 * 75;
    const size_t N1 = 1024UL * 49 * 75;
    const size_t N2 = 1920000UL;
    const size_t N3 = 76800UL;
    for (size_t idx = (size_t)blockIdx.x * blockDim.x + threadIdx.x;
         idx < N0 + N1 + N2 + N3; idx += (size_t)gridDim.x * blockDim.x) {
        if (idx < N0) {
            pose_bf[idx] = f2bf(pose[idx]);
        } else if (idx < N0 + N1) {
            const size_t i = idx - N0;
            const int f = (int)(i % 75);
            const size_t rem = i / 75;
            const int t = (int)(rem % 49);
            const size_t b = rem / 49;
            float v = pose[(b * 50 + t + 1) * 75 + f] - pose[(b * 50 + t) * 75 + f];
            if (noise[(b * 50 + t + 1) * 25 + f / 3] == 1) v = 0.f;
            const ushort_t vb = f2bf(v);
            vel_bf[i] = vb;
            if (t == 0)  A_ve0[b * KP_ + 1024 + f]  = vb;
            if (t == 48) A_dec0[b * KP_ + 1024 + f] = vb;
        } else if (idx < N0 + N1 + N2) {
            const size_t i = idx - N0 - N1;
            out[i] = fut[i];
        } else {
            const size_t i = idx - N0 - N1 - N2;
            const size_t b = i / 75;
            const int f = (int)(i % 75);
            const float p0 = pose[b * 50 * 75 + f];
            A_pe0[b * KP_ + 1024 + f] = f2bf(p0);
            accp[i] = p0;
            out[OFF_CP + b * 50 * 75 + f] = p0;
        }
    }
}

// ---------------------------------------------------------------------------
// Multi-dispatch fallback (round-3 structure, proven 4.06 ms) — used only if
// the cooperative launch is rejected.
// ---------------------------------------------------------------------------
__device__ __forceinline__ void fb_body(
    char* lds,
    const ushort_t* __restrict__ Ain, ushort_t* __restrict__ Aout,
    const ushort_t* __restrict__ Wt,  const float* __restrict__ bias,
    float* __restrict__ cst,
    const ushort_t* xnext, int xstride,
    int ct, int rt, int tid)
{
    const int w = tid >> 6, l = tid & 63;
    const int j0 = ct * 64, row0 = rt * 64;
    if (ct == 0 && xnext) {
        for (int idx = tid; idx < 64 * 96; idx += 256) {
            const int r = idx / 96, xi = idx - r * 96;
            ushort_t v = (xi < FEAT_) ? xnext[(size_t)(row0 + r) * xstride + xi] : (ushort_t)0;
            Aout[(size_t)(row0 + r) * KP_ + 1024 + xi] = v;
        }
    }
    asm volatile("s_waitcnt vmcnt(0)" ::: "memory");
    const int lc4 = l & 3, lr4 = l >> 2;
    const int csrc = lc4 ^ (lr4 & 3);
    const ushort_t* agsrc = Ain + (size_t)(row0 + w * 16 + lr4) * KP_ + csrc * 8;
    char* aldst = lds + (w * 16) * 64;
    const ushort_t* bgsrc[4]; char* bldst[4];
    #pragma unroll
    for (int i = 0; i < 4; ++i) {
        bgsrc[i] = Wt + (size_t)(w * 1024 + j0 + i * 16 + lr4) * KP_ + csrc * 8;
        bldst[i] = lds + 4096 + (w * 64 + i * 16) * 64;
    }
    const int chsw = (((l >> 4) ^ (l & 3)) << 4);
    int aoff[4], boff[4];
    #pragma unroll
    for (int m = 0; m < 4; ++m) aoff[m] = (m * 16 + (l & 15)) * 64 + chsw;
    #pragma unroll
    for (int g = 0; g < 4; ++g) boff[g] = 4096 + (g * 64 + w * 16 + (l & 15)) * 64 + chsw;
    f32x4 acc[4][4];
    #pragma unroll
    for (int m = 0; m < 4; ++m)
        #pragma unroll
        for (int g = 0; g < 4; ++g) acc[m][g] = (f32x4){0.f,0.f,0.f,0.f};
    gload16(agsrc, aldst);
    #pragma unroll
    for (int i = 0; i < 4; ++i) gload16(bgsrc[i], bldst[i]);
    int bi = 0;
    for (int kt = 0; kt < NKT; ++kt) {
        if (kt + 1 < NKT) {
            const size_t k0 = (size_t)(kt + 1) * 32;
            const int nb = (bi ^ 1) * 20480;
            gload16(agsrc + k0, aldst + nb);
            #pragma unroll
            for (int i = 0; i < 4; ++i) gload16(bgsrc[i] + k0, bldst[i] + nb);
            asm volatile("s_waitcnt vmcnt(5)" ::: "memory");
        } else {
            asm volatile("s_waitcnt vmcnt(0)" ::: "memory");
        }
        __builtin_amdgcn_s_barrier();
        asm volatile("" ::: "memory");
        const char* bp = lds + bi * 20480;
        bf16x8 a[4], b[4];
        #pragma unroll
        for (int m = 0; m < 4; ++m) a[m] = *(const bf16x8*)(bp + aoff[m]);
        #pragma unroll
        for (int g = 0; g < 4; ++g) b[g] = *(const bf16x8*)(bp + boff[g]);
        #pragma unroll
        for (int m = 0; m < 4; ++m)
            #pragma unroll
            for (int g = 0; g < 4; ++g)
                acc[m][g] = __builtin_amdgcn_mfma_f32_16x16x32_bf16(a[m], b[g], acc[m][g], 0, 0, 0);
        asm volatile("" ::: "memory");
        __builtin_amdgcn_s_barrier();
        bi ^= 1;
    }
    const int jw = j0 + w * 16 + (l & 15);
    const float b_i = bias[jw], b_f = bias[1024 + jw], b_g = bias[2048 + jw], b_o = bias[3072 + jw];
    #pragma unroll
    for (int m = 0; m < 4; ++m)
        #pragma unroll
        for (int r = 0; r < 4; ++r) {
            const int grow = row0 + m * 16 + ((l >> 4) << 2) + r;
            const float cn = sigm(acc[m][1][r] + b_f) * cst[(size_t)grow * H_ + jw]
                           + sigm(acc[m][0][r] + b_i) * tanhf(acc[m][2][r] + b_g);
            cst[(size_t)grow * H_ + jw] = cn;
            Aout[(size_t)grow * KP_ + jw] = f2bf(sigm(acc[m][3][r] + b_o) * tanhf(cn));
        }
}

struct StepArgs {
    const ushort_t* Ain[2]; ushort_t* Aout[2];
    const ushort_t* W[2]; const float* bias[2]; float* c[2];
    const ushort_t* xnext[2]; int xstride[2];
};

__global__ __launch_bounds__(256)
void fb_step_kernel(StepArgs sa)
{
    __shared__ __align__(16) char lds[2 * 20480];
    const int flat = blockIdx.x, xcd = flat & 7, slot = flat >> 3;
    int pp, ct;
    if (gridDim.x == 512) { const int cgx = (xcd << 2) + (slot >> 4); pp = cgx >> 4; ct = cgx & 15; }
    else                  { const int cgx = (xcd << 1) + (slot >> 4); pp = 0;        ct = cgx; }
    fb_body(lds, sa.Ain[pp], sa.Aout[pp], sa.W[pp], sa.bias[pp], sa.c[pp],
            sa.xnext[pp], sa.xstride[pp], ct, slot & 15, threadIdx.x);
}

__global__ __launch_bounds__(256)
void fb_combine_kernel(const ushort_t* hpe, const ushort_t* hve,
                       const float* cpe, const float* cve,
                       ushort_t* Adec0, float* cde)
{
    const int idx = blockIdx.x * 256 + threadIdx.x;
    if (idx >= B_ * H_) return;
    const size_t o = (size_t)(idx >> 10) * KP_ + (idx & 1023);
    Adec0[o] = f2bf(bf2f(hpe[o]) + bf2f(hve[o]));
    cde[idx] = cpe[idx] + cve[idx];
}

__global__ __launch_bounds__(128)
void fb_fc_kernel(ushort_t* __restrict__ Adec,
                  const ushort_t* __restrict__ fcWb, const float* __restrict__ fcb,
                  float* __restrict__ accp, float* __restrict__ out, int t)
{
    __shared__ float hsf[1024];
    const int b = blockIdx.x;
    {
        const int k = threadIdx.x * 8;
        const bf16x8 v = *(const bf16x8*)(Adec + (size_t)b * KP_ + k);
        #pragma unroll
        for (int u = 0; u < 8; ++u) hsf[k + u] = bf2f((ushort_t)v[u]);
    }
    __syncthreads();
    const int f = threadIdx.x;
    if (f < FEAT_) {
        const ushort_t* wr = fcWb + (size_t)f * 1024;
        float s0 = fcb[f], s1 = 0.f, s2 = 0.f, s3 = 0.f;
        for (int k = 0; k < 1024; k += 32) {
            const bf16x8 w0 = *(const bf16x8*)(wr + k);
            const bf16x8 w1 = *(const bf16x8*)(wr + k + 8);
            const bf16x8 w2 = *(const bf16x8*)(wr + k + 16);
            const bf16x8 w3 = *(const bf16x8*)(wr + k + 24);
            #pragma unroll
            for (int u = 0; u < 8; ++u) {
                s0 = fmaf(hsf[k + u],      bf2f((ushort_t)w0[u]), s0);
                s1 = fmaf(hsf[k + 8 + u],  bf2f((ushort_t)w1[u]), s1);
                s2 = fmaf(hsf[k + 16 + u], bf2f((ushort_t)w2[u]), s2);
                s3 = fmaf(hsf[k + 24 + u], bf2f((ushort_t)w3[u]), s3);
            }
        }
        float s = (s0 + s1) + (s2 + s3);
        s = fminf(fmaxf(s, -1.f), 1.f);
        const float pnew = accp[b * FEAT_ + f] + s;
        accp[b * FEAT_ + f] = pnew;
        out[OFF_CV + ((size_t)b * 49 + t) * FEAT_ + f]     = s;
        out[OFF_CP + ((size_t)b * 50 + t + 1) * FEAT_ + f] = pnew;
        Adec[(size_t)b * KP_ + 1024 + f] = f2bf(s);
    }
}

extern "C" void kernel_launch(void* const* d_in, const int* in_sizes, int n_in,
                              void* d_out, int out_size, void* d_ws, size_t ws_size,
                              hipStream_t stream) {
    const float* pose   = (const float*)d_in[0];
    const float* fut    = (const float*)d_in[1];
    const int*   noise  = (const int*)  d_in[2];
    const float* peWih  = (const float*)d_in[3];
    const float* peWhh  = (const float*)d_in[4];
    const float* pe_bih = (const float*)d_in[5];
    const float* pe_bhh = (const float*)d_in[6];
    const float* veWih  = (const float*)d_in[7];
    const float* veWhh  = (const float*)d_in[8];
    const float* ve_bih = (const float*)d_in[9];
    const float* ve_bhh = (const float*)d_in[10];
    const float* deWih  = (const float*)d_in[11];
    const float* deWhh  = (const float*)d_in[12];
    const float* de_bih = (const float*)d_in[13];
    const float* de_bhh = (const float*)d_in[14];
    const float* fcW    = (const float*)d_in[15];
    const float* fcb    = (const float*)d_in[16];
    float* out = (float*)d_out;

    char* base = (char*)d_ws;
    ushort_t* Ape[2]  = {(ushort_t*)(base + 0UL * 2293760), (ushort_t*)(base + 1UL * 2293760)};
    ushort_t* Ave[2]  = {(ushort_t*)(base + 2UL * 2293760), (ushort_t*)(base + 3UL * 2293760)};
    ushort_t* Adec[2] = {(ushort_t*)(base + 4UL * 2293760), (ushort_t*)(base + 5UL * 2293760)};
    float* c_pe = (float*)(base + 13762560);
    float* c_ve = c_pe + 1048576;
    float* c_de = c_ve + 1048576;
    ushort_t* Wp    = (ushort_t*)(base + 26345472);   // 3 x 4096 x 1120
    float*    biasp = (float*)   (base + 53870592);   // 3 x 4096
    ushort_t* fcWb  = (ushort_t*)(base + 53919744);   // 75 x 1024
    ushort_t* pose_bf = (ushort_t*)(base + 54073344); // 1024x50x75
    ushort_t* vel_bf  = (ushort_t*)(base + 61753344); // 1024x49x75
    float*    accp    = (float*)   (base + 69279744); // 1024x75

    hipMemsetAsync(base, 0, 13762560, stream);   // 6 A buffers

    pack_kernel<<<2048, 256, 0, stream>>>(peWih, peWhh, veWih, veWhh, deWih, deWhh,
                                          pe_bih, pe_bhh, ve_bih, ve_bhh, de_bih, de_bhh,
                                          fcW, Wp, biasp, fcWb);
    prep_kernel<<<2048, 256, 0, stream>>>(pose, fut, noise, pose_bf, vel_bf,
                                          Ape[0], Ave[0], Adec[0], accp, out);

    MainArgs ma;
    ma.A[0][0] = Ape[0];  ma.A[0][1] = Ape[1];
    ma.A[1][0] = Ave[0];  ma.A[1][1] = Ave[1];
    ma.A[2][0] = Adec[0]; ma.A[2][1] = Adec[1];
    ma.W[0] = Wp; ma.W[1] = Wp + 4587520; ma.W[2] = Wp + 9175040;
    ma.bias[0] = biasp; ma.bias[1] = biasp + 4096; ma.bias[2] = biasp + 8192;
    ma.c_pe = c_pe; ma.c_ve = c_ve;
    ma.pose_bf = pose_bf; ma.vel_bf = vel_bf;
    ma.fcWb = fcWb; ma.fcb = fcb; ma.accp = accp; ma.out = out;

    void* kargs[] = {(void*)&ma};
    hipError_t e = hipLaunchCooperativeKernel((const void*)main_kernel,
                                              dim3(512), dim3(512), kargs, 0, stream);
    if (e != hipSuccess) {
        (void)hipGetLastError();
        // ---- proven multi-dispatch fallback (round-3 path, ~4.06 ms) ----
        for (int t = 0; t < 49; ++t) {
            StepArgs sa;
            sa.Ain[0] = Ape[t & 1];  sa.Aout[0] = Ape[(t + 1) & 1];
            sa.W[0] = ma.W[0]; sa.bias[0] = biasp; sa.c[0] = c_pe;
            sa.xnext[0] = pose_bf + (size_t)(t + 1) * 75; sa.xstride[0] = 3750;
            sa.Ain[1] = Ave[t & 1];  sa.Aout[1] = Ave[(t + 1) & 1];
            sa.W[1] = ma.W[1]; sa.bias[1] = biasp + 4096; sa.c[1] = c_ve;
            sa.xnext[1] = (t < 48) ? (vel_bf + (size_t)(t + 1) * 75) : nullptr;
            sa.xstride[1] = 3675;
            fb_step_kernel<<<512, 256, 0, stream>>>(sa);
        }
        {
            StepArgs sa;
            sa.Ain[0] = Ape[1]; sa.Aout[0] = Ape[0];
            sa.W[0] = ma.W[0]; sa.bias[0] = biasp; sa.c[0] = c_pe;
            sa.xnext[0] = nullptr; sa.xstride[0] = 3750;
            sa.Ain[1] = sa.Ain[0]; sa.Aout[1] = sa.Aout[0];
            sa.W[1] = sa.W[0]; sa.bias[1] = sa.bias[0]; sa.c[1] = sa.c[0];
            sa.xnext[1] = nullptr; sa.xstride[1] = 3750;
            fb_step_kernel<<<256, 256, 0, stream>>>(sa);
        }
        fb_combine_kernel<<<4096, 256, 0, stream>>>(Ape[0], Ave[1], c_pe, c_ve, Adec[0], c_de);
        for (int d = 0; d < 49; ++d) {
            StepArgs sa;
            sa.Ain[0] = Adec[d & 1]; sa.Aout[0] = Adec[(d + 1) & 1];
            sa.W[0] = ma.W[2]; sa.bias[0] = biasp + 8192; sa.c[0] = c_de;
            sa.xnext[0] = nullptr; sa.xstride[0] = 0;
            sa.Ain[1] = sa.Ain[0]; sa.Aout[1] = sa.Aout[0];
            sa.W[1] = sa.W[0]; sa.bias[1] = sa.bias[0]; sa.c[1] = sa.c[0];
            sa.xnext[1] = nullptr; sa.xstride[1] = 0;
            fb_step_kernel<<<256, 256, 0, stream>>>(sa);
            fb_fc_kernel<<<B_, 128, 0, stream>>>(Adec[(d + 1) & 1], fcWb, fcb, accp, out, d);
        }
    }
}

// Round 10
// 7845.764 us; speedup vs baseline: 1.8535x; 1.8535x over previous
//
#include <hip/hip_runtime.h>
#include <hip/hip_cooperative_groups.h>

namespace cg = cooperative_groups;

typedef unsigned short ushort_t;
typedef __attribute__((ext_vector_type(8))) short bf16x8;
typedef __attribute__((ext_vector_type(4))) float f32x4;

#define B_    1024
#define H_    1024
#define FEAT_ 75
#define KP_   1120          // packed K: 1024 h + 75 x + 21 zero pad
#define NKT   35            // K-chunks of 32
#define WROWB 2256          // LDS W row bytes (1128 elems, bank-skewed: 564%32=20 -> 2-way max)
#define LDS_W  144384       // 64 rows x 2256 B
#define LDS_FC 144384       // fc h staging (4 x 1024 bf16 = 8 KB) overlays nothing
#define LDS_TOT 152576
#define OFF_CP 1920000UL    // 1024*25*75
#define OFF_CV 5760000UL    // OFF_CP + 1024*50*75

__device__ __forceinline__ float bf2f(ushort_t u) {
    unsigned x = ((unsigned)u) << 16;
    float f; __builtin_memcpy(&f, &x, 4); return f;
}
__device__ __forceinline__ ushort_t f2bf(float f) {
    unsigned x; __builtin_memcpy(&x, &f, 4);
    x += 0x7fffu + ((x >> 16) & 1u);          // RNE
    return (ushort_t)(x >> 16);
}
__device__ __forceinline__ float sigm(float x) { return 1.f / (1.f + __expf(-x)); }

__device__ __forceinline__ void gload16(const void* g, void* l) {
    __builtin_amdgcn_global_load_lds(
        (const __attribute__((address_space(1))) void*)g,
        (__attribute__((address_space(3))) void*)l, 16, 0, 0);
}

// ---------------------------------------------------------------------------
// Stage this block's W slice (64 gate-cols x 1120 K) into LDS, once.
// Gate-row r = g*16 + jj  ->  global row g*1024 + j0 + jj.
// ---------------------------------------------------------------------------
__device__ __forceinline__ void load_w_lds(char* lds, const ushort_t* __restrict__ Wt,
                                           int j0, int tid)
{
    for (int idx = tid; idx < 64 * 140; idx += 512) {
        const int r  = idx / 140;
        const int cc = idx - r * 140;
        const int grow = ((r >> 4) << 10) + j0 + (r & 15);
        *(bf16x8*)(lds + r * WROWB + cc * 16) =
            *(const bf16x8*)(Wt + (size_t)grow * KP_ + cc * 8);
    }
}

// ---------------------------------------------------------------------------
// One LSTM step for M m-tiles (M*16 rows) x 64 gate-cols. W from LDS (static,
// no barriers); A from global (L2/L3) straight to registers; c in registers.
// N-tile index == gate index -> all 4 gates in-lane, no transpose.
// ---------------------------------------------------------------------------
template<int M>
__device__ __forceinline__ void gstep(
    const char* lds, const ushort_t* __restrict__ Ain, ushort_t* __restrict__ Aout,
    float (&cr)[M][4], float bsi, float bsf, float bsg, float bso,
    int rowbase, int j0, int l, int write_c, float* __restrict__ cglob)
{
    f32x4 acc[M][4];
    #pragma unroll
    for (int m = 0; m < M; ++m)
        #pragma unroll
        for (int g = 0; g < 4; ++g)
            acc[m][g] = (f32x4){0.f, 0.f, 0.f, 0.f};

    const ushort_t* ap = Ain + (size_t)(rowbase + (l & 15)) * KP_ + ((l >> 4) << 3);
    const char*     bp = lds + (size_t)(l & 15) * WROWB + (((l >> 4) << 3) << 1);

    for (int kt = 0; kt < NKT; ++kt) {
        bf16x8 af[M], bfr[4];
        #pragma unroll
        for (int m = 0; m < M; ++m)
            af[m] = *(const bf16x8*)(ap + (size_t)m * 16 * KP_ + kt * 32);
        #pragma unroll
        for (int g = 0; g < 4; ++g)
            bfr[g] = *(const bf16x8*)(bp + (size_t)g * 16 * WROWB + kt * 64);
        #pragma unroll
        for (int m = 0; m < M; ++m)
            #pragma unroll
            for (int g = 0; g < 4; ++g)
                acc[m][g] = __builtin_amdgcn_mfma_f32_16x16x32_bf16(af[m], bfr[g], acc[m][g], 0, 0, 0);
    }

    const int jc = j0 + (l & 15);
    #pragma unroll
    for (int m = 0; m < M; ++m) {
        #pragma unroll
        for (int r = 0; r < 4; ++r) {
            const int row = rowbase + m * 16 + ((l >> 4) << 2) + r;
            const float gi = acc[m][0][r] + bsi;
            const float gf = acc[m][1][r] + bsf;
            const float gg = acc[m][2][r] + bsg;
            const float go = acc[m][3][r] + bso;
            const float cn = sigm(gf) * cr[m][r] + sigm(gi) * tanhf(gg);
            cr[m][r] = cn;
            Aout[(size_t)row * KP_ + jc] = f2bf(sigm(go) * tanhf(cn));
            if (write_c) cglob[((size_t)row << 10) + jc] = cn;
        }
    }
}

// ---------------------------------------------------------------------------
// fc phase (decoder): 256 blocks x 4 rows. h staged bf16 in spare LDS.
// Fuses clip, comp_vel/comp_pose writes, cumsum, bf16 x-feedback.
// ---------------------------------------------------------------------------
__device__ __forceinline__ void fc_phase(
    char* lds, ushort_t* __restrict__ Ah,
    const ushort_t* __restrict__ fcWb, const float* __restrict__ fcb,
    float* __restrict__ accp, float* __restrict__ out,
    int d, int tid, int blk)
{
    ushort_t* hs = (ushort_t*)(lds + LDS_FC);
    const int r0 = blk * 4;
    {
        const int idx = tid * 8;            // 4096 elems / 512 thr
        const int r = idx >> 10, k = idx & 1023;
        *(bf16x8*)(hs + (r << 10) + k) = *(const bf16x8*)(Ah + (size_t)(r0 + r) * KP_ + k);
    }
    __syncthreads();
    const int r = tid >> 7, f = tid & 127;
    if (f < FEAT_) {
        const ushort_t* hr = hs + (r << 10);
        const ushort_t* wr = fcWb + (size_t)f * 1024;
        float s0 = fcb[f], s1 = 0.f, s2 = 0.f, s3 = 0.f;
        for (int k = 0; k < 1024; k += 32) {
            const bf16x8 h0 = *(const bf16x8*)(hr + k);
            const bf16x8 h1 = *(const bf16x8*)(hr + k + 8);
            const bf16x8 h2 = *(const bf16x8*)(hr + k + 16);
            const bf16x8 h3 = *(const bf16x8*)(hr + k + 24);
            const bf16x8 w0 = *(const bf16x8*)(wr + k);
            const bf16x8 w1 = *(const bf16x8*)(wr + k + 8);
            const bf16x8 w2 = *(const bf16x8*)(wr + k + 16);
            const bf16x8 w3 = *(const bf16x8*)(wr + k + 24);
            #pragma unroll
            for (int u = 0; u < 8; ++u) {
                s0 = fmaf(bf2f((ushort_t)h0[u]), bf2f((ushort_t)w0[u]), s0);
                s1 = fmaf(bf2f((ushort_t)h1[u]), bf2f((ushort_t)w1[u]), s1);
                s2 = fmaf(bf2f((ushort_t)h2[u]), bf2f((ushort_t)w2[u]), s2);
                s3 = fmaf(bf2f((ushort_t)h3[u]), bf2f((ushort_t)w3[u]), s3);
            }
        }
        float s = (s0 + s1) + (s2 + s3);
        s = fminf(fmaxf(s, -1.f), 1.f);
        const int row = r0 + r;
        const float pnew = accp[row * FEAT_ + f] + s;
        accp[row * FEAT_ + f] = pnew;
        out[OFF_CV + ((size_t)row * 49 + d) * FEAT_ + f]     = s;
        out[OFF_CP + ((size_t)row * 50 + d + 1) * FEAT_ + f] = pnew;
        Ah[(size_t)row * KP_ + 1024 + f] = f2bf(s);
    }
    __syncthreads();
}

// ---------------------------------------------------------------------------
struct MainArgs {
    ushort_t*       A[3][2];     // [pe,ve,dec][ping,pong] 1024 x KP_ bf16
    const ushort_t* W[3];        // packed 4096 x KP_ bf16
    const float*    bias[3];
    float*          c_pe; float* c_ve;
    const ushort_t* pose_bf; const ushort_t* vel_bf;
    const ushort_t* fcWb; const float* fcb;
    float*          accp; float* out;
};

// ---------------------------------------------------------------------------
// Persistent cooperative kernel: 256 blocks x 512 threads, 1 block/CU.
// W LDS-resident per block (written once per LSTM) -> zero W traffic for all
// 99 steps; A streamed from L2/L3 (caches persist across grid.sync, proven
// round 7: 112 MB total FETCH). K-loop has NO barriers.
// ---------------------------------------------------------------------------
__global__ __launch_bounds__(512, 2)
void main_kernel(MainArgs ma)
{
    cg::grid_group grid = cg::this_grid();
    __shared__ __align__(16) char lds[LDS_TOT];
    const int tid = threadIdx.x;
    const int wv = tid >> 6, l = tid & 63;
    const int blk = blockIdx.x;

    // ---- encoder geometry: 128 blocks/problem, 64 strips x 2 row-halves ----
    const int p     = blk >> 7;
    const int pi    = blk & 127;
    const int strip = pi >> 1;
    const int half  = pi & 1;
    const int j0    = strip * 16;
    const int rowb  = half * 512 + wv * 64;

    load_w_lds(lds, ma.W[p], j0, tid);
    __syncthreads();

    const int jl = j0 + (l & 15);
    float bsi = ma.bias[p][jl];
    float bsf = ma.bias[p][1024 + jl];
    float bsg = ma.bias[p][2048 + jl];
    float bso = ma.bias[p][3072 + jl];

    float ce[4][4];
    #pragma unroll
    for (int m = 0; m < 4; ++m)
        #pragma unroll
        for (int r = 0; r < 4; ++r) ce[m][r] = 0.f;

    float* cglob = (p == 0) ? ma.c_pe : ma.c_ve;
    const int tlast = (p == 0) ? 49 : 48;

    // ---------------- encoders: 50 steps ----------------
    for (int t = 0; t < 50; ++t) {
        if (p == 0 || t < 49) {
            const ushort_t* Ain = ma.A[p][t & 1];
            ushort_t* Aout = ma.A[p][(t + 1) & 1];
            // x_{t+1} copy: this block copies its 8 rows
            const ushort_t* xn = nullptr; int xstr = 0;
            if (p == 0 && t < 49) { xn = ma.pose_bf + (size_t)(t + 1) * 75; xstr = 3750; }
            if (p == 1 && t < 48) { xn = ma.vel_bf  + (size_t)(t + 1) * 75; xstr = 3675; }
            if (xn) {
                for (int i = tid; i < 600; i += 512) {
                    const int r = i / 75, f = i - (i / 75) * 75;
                    Aout[(size_t)(pi * 8 + r) * KP_ + 1024 + f] =
                        xn[(size_t)(pi * 8 + r) * xstr + f];
                }
            }
            gstep<4>(lds, Ain, Aout, ce, bsi, bsf, bsg, bso,
                     rowb, j0, l, (t == tlast), cglob);
        }
        grid.sync();
    }

    // ---------------- combine: h_dec0 = h_pe + h_ve ----------------
    {
        const ushort_t* hpe = ma.A[0][0];
        const ushort_t* hve = ma.A[1][1];
        ushort_t* Ad = ma.A[2][0];
        for (int k = tid; k < 4096; k += 512) {
            const int idx = (blk << 12) + k;
            const size_t o = (size_t)(idx >> 10) * KP_ + (idx & 1023);
            Ad[o] = f2bf(bf2f(hpe[o]) + bf2f(hve[o]));
        }
    }
    __threadfence();
    grid.sync();

    // ---------------- decoder: reload W slice, init c from c_pe+c_ve -------
    const int qd  = blk & 3;
    const int sd  = blk >> 2;
    const int j0d = sd * 16;
    const int rowbd = qd * 256 + wv * 32;
    load_w_lds(lds, ma.W[2], j0d, tid);
    __syncthreads();

    const int jld = j0d + (l & 15);
    bsi = ma.bias[2][jld];
    bsf = ma.bias[2][1024 + jld];
    bsg = ma.bias[2][2048 + jld];
    bso = ma.bias[2][3072 + jld];

    float cd[2][4];
    #pragma unroll
    for (int m = 0; m < 2; ++m)
        #pragma unroll
        for (int r = 0; r < 4; ++r) {
            const int row = rowbd + m * 16 + ((l >> 4) << 2) + r;
            const size_t o = ((size_t)row << 10) + jld;
            cd[m][r] = ma.c_pe[o] + ma.c_ve[o];
        }

    // ---------------- decoder: 49 x (step ; fc) ----------------
    for (int d = 0; d < 49; ++d) {
        gstep<2>(lds, ma.A[2][d & 1], ma.A[2][(d + 1) & 1], cd,
                 bsi, bsf, bsg, bso, rowbd, j0d, l, 0, nullptr);
        grid.sync();
        fc_phase(lds, ma.A[2][(d + 1) & 1], ma.fcWb, ma.fcb, ma.accp, ma.out, d, tid, blk);
        grid.sync();
    }
}

// ---------------------------------------------------------------------------
// Pack / prep (proven, unchanged).
// ---------------------------------------------------------------------------
__global__ __launch_bounds__(256)
void pack_kernel(const float* __restrict__ peWih, const float* __restrict__ peWhh,
                 const float* __restrict__ veWih, const float* __restrict__ veWhh,
                 const float* __restrict__ deWih, const float* __restrict__ deWhh,
                 const float* __restrict__ pe_bih, const float* __restrict__ pe_bhh,
                 const float* __restrict__ ve_bih, const float* __restrict__ ve_bhh,
                 const float* __restrict__ de_bih, const float* __restrict__ de_bhh,
                 const float* __restrict__ fcW,
                 ushort_t* __restrict__ Wp, float* __restrict__ biasp,
                 ushort_t* __restrict__ fcWb)
{
    const size_t PER = 4096UL * KP_;
    const size_t NW  = 3UL * PER;
    const size_t NB  = 3UL * 4096;
    const size_t NF  = 75UL * 1024;
    for (size_t idx = (size_t)blockIdx.x * blockDim.x + threadIdx.x;
         idx < NW + NB + NF; idx += (size_t)gridDim.x * blockDim.x) {
        if (idx < NW) {
            const int pp  = (int)(idx / PER);
            const size_t rem = idx % PER;
            const int row = (int)(rem / KP_);
            const int k   = (int)(rem % KP_);
            const float* Whh = (pp == 0) ? peWhh : (pp == 1) ? veWhh : deWhh;
            const float* Wih = (pp == 0) ? peWih : (pp == 1) ? veWih : deWih;
            float v = 0.f;
            if (k < 1024)      v = Whh[(size_t)row * 1024 + k];
            else if (k < 1099) v = Wih[(size_t)row * 75 + (k - 1024)];
            Wp[idx] = f2bf(v);
        } else if (idx < NW + NB) {
            const size_t i = idx - NW;
            const int pp = (int)(i / 4096);
            const int r = (int)(i % 4096);
            const float* bih = (pp == 0) ? pe_bih : (pp == 1) ? ve_bih : de_bih;
            const float* bhh = (pp == 0) ? pe_bhh : (pp == 1) ? ve_bhh : de_bhh;
            biasp[i] = bih[r] + bhh[r];
        } else {
            const size_t i = idx - NW - NB;
            fcWb[i] = f2bf(fcW[i]);
        }
    }
}

__global__ __launch_bounds__(256)
void prep_kernel(const float* __restrict__ pose, const float* __restrict__ fut,
                 const int* __restrict__ noise,
                 ushort_t* __restrict__ pose_bf, ushort_t* __restrict__ vel_bf,
                 ushort_t* __restrict__ A_pe0, ushort_t* __restrict__ A_ve0,
                 ushort_t* __restrict__ A_dec0,
                 float* __restrict__ accp, float* __restrict__ out)
{
    const size_t N0 = 1024UL * 50 * 75;
    const size_t N1 = 1024UL * 49 * 75;
    const size_t N2 = 1920000UL;
    const size_t N3 = 76800UL;
    for (size_t idx = (size_t)blockIdx.x * blockDim.x + threadIdx.x;
         idx < N0 + N1 + N2 + N3; idx += (size_t)gridDim.x * blockDim.x) {
        if (idx < N0) {
            pose_bf[idx] = f2bf(pose[idx]);
        } else if (idx < N0 + N1) {
            const size_t i = idx - N0;
            const int f = (int)(i % 75);
            const size_t rem = i / 75;
            const int t = (int)(rem % 49);
            const size_t b = rem / 49;
            float v = pose[(b * 50 + t + 1) * 75 + f] - pose[(b * 50 + t) * 75 + f];
            if (noise[(b * 50 + t + 1) * 25 + f / 3] == 1) v = 0.f;
            const ushort_t vb = f2bf(v);
            vel_bf[i] = vb;
            if (t == 0)  A_ve0[b * KP_ + 1024 + f]  = vb;
            if (t == 48) A_dec0[b * KP_ + 1024 + f] = vb;
        } else if (idx < N0 + N1 + N2) {
            const size_t i = idx - N0 - N1;
            out[i] = fut[i];
        } else {
            const size_t i = idx - N0 - N1 - N2;
            const size_t b = i / 75;
            const int f = (int)(i % 75);
            const float p0 = pose[b * 50 * 75 + f];
            A_pe0[b * KP_ + 1024 + f] = f2bf(p0);
            accp[i] = p0;
            out[OFF_CP + b * 50 * 75 + f] = p0;
        }
    }
}

// ---------------------------------------------------------------------------
// Multi-dispatch fallback (round-3 structure, proven 4.06 ms) — used only if
// the cooperative launch is rejected.
// ---------------------------------------------------------------------------
__device__ __forceinline__ void fb_body(
    char* lds,
    const ushort_t* __restrict__ Ain, ushort_t* __restrict__ Aout,
    const ushort_t* __restrict__ Wt,  const float* __restrict__ bias,
    float* __restrict__ cst,
    const ushort_t* xnext, int xstride,
    int ct, int rt, int tid)
{
    const int w = tid >> 6, l = tid & 63;
    const int j0 = ct * 64, row0 = rt * 64;
    if (ct == 0 && xnext) {
        for (int idx = tid; idx < 64 * 96; idx += 256) {
            const int r = idx / 96, xi = idx - r * 96;
            ushort_t v = (xi < FEAT_) ? xnext[(size_t)(row0 + r) * xstride + xi] : (ushort_t)0;
            Aout[(size_t)(row0 + r) * KP_ + 1024 + xi] = v;
        }
    }
    asm volatile("s_waitcnt vmcnt(0)" ::: "memory");
    const int lc4 = l & 3, lr4 = l >> 2;
    const int csrc = lc4 ^ (lr4 & 3);
    const ushort_t* agsrc = Ain + (size_t)(row0 + w * 16 + lr4) * KP_ + csrc * 8;
    char* aldst = lds + (w * 16) * 64;
    const ushort_t* bgsrc[4]; char* bldst[4];
    #pragma unroll
    for (int i = 0; i < 4; ++i) {
        bgsrc[i] = Wt + (size_t)(w * 1024 + j0 + i * 16 + lr4) * KP_ + csrc * 8;
        bldst[i] = lds + 4096 + (w * 64 + i * 16) * 64;
    }
    const int chsw = (((l >> 4) ^ (l & 3)) << 4);
    int aoff[4], boff[4];
    #pragma unroll
    for (int m = 0; m < 4; ++m) aoff[m] = (m * 16 + (l & 15)) * 64 + chsw;
    #pragma unroll
    for (int g = 0; g < 4; ++g) boff[g] = 4096 + (g * 64 + w * 16 + (l & 15)) * 64 + chsw;
    f32x4 acc[4][4];
    #pragma unroll
    for (int m = 0; m < 4; ++m)
        #pragma unroll
        for (int g = 0; g < 4; ++g) acc[m][g] = (f32x4){0.f,0.f,0.f,0.f};
    gload16(agsrc, aldst);
    #pragma unroll
    for (int i = 0; i < 4; ++i) gload16(bgsrc[i], bldst[i]);
    int bi = 0;
    for (int kt = 0; kt < NKT; ++kt) {
        if (kt + 1 < NKT) {
            const size_t k0 = (size_t)(kt + 1) * 32;
            const int nb = (bi ^ 1) * 20480;
            gload16(agsrc + k0, aldst + nb);
            #pragma unroll
            for (int i = 0; i < 4; ++i) gload16(bgsrc[i] + k0, bldst[i] + nb);
            asm volatile("s_waitcnt vmcnt(5)" ::: "memory");
        } else {
            asm volatile("s_waitcnt vmcnt(0)" ::: "memory");
        }
        __builtin_amdgcn_s_barrier();
        asm volatile("" ::: "memory");
        const char* bp = lds + bi * 20480;
        bf16x8 a[4], b[4];
        #pragma unroll
        for (int m = 0; m < 4; ++m) a[m] = *(const bf16x8*)(bp + aoff[m]);
        #pragma unroll
        for (int g = 0; g < 4; ++g) b[g] = *(const bf16x8*)(bp + boff[g]);
        #pragma unroll
        for (int m = 0; m < 4; ++m)
            #pragma unroll
            for (int g = 0; g < 4; ++g)
                acc[m][g] = __builtin_amdgcn_mfma_f32_16x16x32_bf16(a[m], b[g], acc[m][g], 0, 0, 0);
        asm volatile("" ::: "memory");
        __builtin_amdgcn_s_barrier();
        bi ^= 1;
    }
    const int jw = j0 + w * 16 + (l & 15);
    const float b_i = bias[jw], b_f = bias[1024 + jw], b_g = bias[2048 + jw], b_o = bias[3072 + jw];
    #pragma unroll
    for (int m = 0; m < 4; ++m)
        #pragma unroll
        for (int r = 0; r < 4; ++r) {
            const int grow = row0 + m * 16 + ((l >> 4) << 2) + r;
            const float cn = sigm(acc[m][1][r] + b_f) * cst[(size_t)grow * H_ + jw]
                           + sigm(acc[m][0][r] + b_i) * tanhf(acc[m][2][r] + b_g);
            cst[(size_t)grow * H_ + jw] = cn;
            Aout[(size_t)grow * KP_ + jw] = f2bf(sigm(acc[m][3][r] + b_o) * tanhf(cn));
        }
}

struct StepArgs {
    const ushort_t* Ain[2]; ushort_t* Aout[2];
    const ushort_t* W[2]; const float* bias[2]; float* c[2];
    const ushort_t* xnext[2]; int xstride[2];
};

__global__ __launch_bounds__(256)
void fb_step_kernel(StepArgs sa)
{
    __shared__ __align__(16) char lds[2 * 20480];
    const int flat = blockIdx.x, xcd = flat & 7, slot = flat >> 3;
    int pp, ct;
    if (gridDim.x == 512) { const int cgx = (xcd << 2) + (slot >> 4); pp = cgx >> 4; ct = cgx & 15; }
    else                  { const int cgx = (xcd << 1) + (slot >> 4); pp = 0;        ct = cgx; }
    fb_body(lds, sa.Ain[pp], sa.Aout[pp], sa.W[pp], sa.bias[pp], sa.c[pp],
            sa.xnext[pp], sa.xstride[pp], ct, slot & 15, threadIdx.x);
}

__global__ __launch_bounds__(256)
void fb_combine_kernel(const ushort_t* hpe, const ushort_t* hve,
                       const float* cpe, const float* cve,
                       ushort_t* Adec0, float* cde)
{
    const int idx = blockIdx.x * 256 + threadIdx.x;
    if (idx >= B_ * H_) return;
    const size_t o = (size_t)(idx >> 10) * KP_ + (idx & 1023);
    Adec0[o] = f2bf(bf2f(hpe[o]) + bf2f(hve[o]));
    cde[idx] = cpe[idx] + cve[idx];
}

__global__ __launch_bounds__(128)
void fb_fc_kernel(ushort_t* __restrict__ Adec,
                  const ushort_t* __restrict__ fcWb, const float* __restrict__ fcb,
                  float* __restrict__ accp, float* __restrict__ out, int t)
{
    __shared__ float hsf[1024];
    const int b = blockIdx.x;
    {
        const int k = threadIdx.x * 8;
        const bf16x8 v = *(const bf16x8*)(Adec + (size_t)b * KP_ + k);
        #pragma unroll
        for (int u = 0; u < 8; ++u) hsf[k + u] = bf2f((ushort_t)v[u]);
    }
    __syncthreads();
    const int f = threadIdx.x;
    if (f < FEAT_) {
        const ushort_t* wr = fcWb + (size_t)f * 1024;
        float s0 = fcb[f], s1 = 0.f, s2 = 0.f, s3 = 0.f;
        for (int k = 0; k < 1024; k += 32) {
            const bf16x8 w0 = *(const bf16x8*)(wr + k);
            const bf16x8 w1 = *(const bf16x8*)(wr + k + 8);
            const bf16x8 w2 = *(const bf16x8*)(wr + k + 16);
            const bf16x8 w3 = *(const bf16x8*)(wr + k + 24);
            #pragma unroll
            for (int u = 0; u < 8; ++u) {
                s0 = fmaf(hsf[k + u],      bf2f((ushort_t)w0[u]), s0);
                s1 = fmaf(hsf[k + 8 + u],  bf2f((ushort_t)w1[u]), s1);
                s2 = fmaf(hsf[k + 16 + u], bf2f((ushort_t)w2[u]), s2);
                s3 = fmaf(hsf[k + 24 + u], bf2f((ushort_t)w3[u]), s3);
            }
        }
        float s = (s0 + s1) + (s2 + s3);
        s = fminf(fmaxf(s, -1.f), 1.f);
        const float pnew = accp[b * FEAT_ + f] + s;
        accp[b * FEAT_ + f] = pnew;
        out[OFF_CV + ((size_t)b * 49 + t) * FEAT_ + f]     = s;
        out[OFF_CP + ((size_t)b * 50 + t + 1) * FEAT_ + f] = pnew;
        Adec[(size_t)b * KP_ + 1024 + f] = f2bf(s);
    }
}

extern "C" void kernel_launch(void* const* d_in, const int* in_sizes, int n_in,
                              void* d_out, int out_size, void* d_ws, size_t ws_size,
                              hipStream_t stream) {
    const float* pose   = (const float*)d_in[0];
    const float* fut    = (const float*)d_in[1];
    const int*   noise  = (const int*)  d_in[2];
    const float* peWih  = (const float*)d_in[3];
    const float* peWhh  = (const float*)d_in[4];
    const float* pe_bih = (const float*)d_in[5];
    const float* pe_bhh = (const float*)d_in[6];
    const float* veWih  = (const float*)d_in[7];
    const float* veWhh  = (const float*)d_in[8];
    const float* ve_bih = (const float*)d_in[9];
    const float* ve_bhh = (const float*)d_in[10];
    const float* deWih  = (const float*)d_in[11];
    const float* deWhh  = (const float*)d_in[12];
    const float* de_bih = (const float*)d_in[13];
    const float* de_bhh = (const float*)d_in[14];
    const float* fcW    = (const float*)d_in[15];
    const float* fcb    = (const float*)d_in[16];
    float* out = (float*)d_out;

    char* base = (char*)d_ws;
    ushort_t* Ape[2]  = {(ushort_t*)(base + 0UL * 2293760), (ushort_t*)(base + 1UL * 2293760)};
    ushort_t* Ave[2]  = {(ushort_t*)(base + 2UL * 2293760), (ushort_t*)(base + 3UL * 2293760)};
    ushort_t* Adec[2] = {(ushort_t*)(base + 4UL * 2293760), (ushort_t*)(base + 5UL * 2293760)};
    float* c_pe = (float*)(base + 13762560);
    float* c_ve = c_pe + 1048576;
    float* c_de = c_ve + 1048576;
    ushort_t* Wp    = (ushort_t*)(base + 26345472);   // 3 x 4096 x 1120
    float*    biasp = (float*)   (base + 53870592);   // 3 x 4096
    ushort_t* fcWb  = (ushort_t*)(base + 53919744);   // 75 x 1024
    ushort_t* pose_bf = (ushort_t*)(base + 54073344); // 1024x50x75
    ushort_t* vel_bf  = (ushort_t*)(base + 61753344); // 1024x49x75
    float*    accp    = (float*)   (base + 69279744); // 1024x75

    hipMemsetAsync(base, 0, 13762560, stream);   // 6 A buffers

    pack_kernel<<<2048, 256, 0, stream>>>(peWih, peWhh, veWih, veWhh, deWih, deWhh,
                                          pe_bih, pe_bhh, ve_bih, ve_bhh, de_bih, de_bhh,
                                          fcW, Wp, biasp, fcWb);
    prep_kernel<<<2048, 256, 0, stream>>>(pose, fut, noise, pose_bf, vel_bf,
                                          Ape[0], Ave[0], Adec[0], accp, out);

    MainArgs ma;
    ma.A[0][0] = Ape[0];  ma.A[0][1] = Ape[1];
    ma.A[1][0] = Ave[0];  ma.A[1][1] = Ave[1];
    ma.A[2][0] = Adec[0]; ma.A[2][1] = Adec[1];
    ma.W[0] = Wp; ma.W[1] = Wp + 4587520; ma.W[2] = Wp + 9175040;
    ma.bias[0] = biasp; ma.bias[1] = biasp + 4096; ma.bias[2] = biasp + 8192;
    ma.c_pe = c_pe; ma.c_ve = c_ve;
    ma.pose_bf = pose_bf; ma.vel_bf = vel_bf;
    ma.fcWb = fcWb; ma.fcb = fcb; ma.accp = accp; ma.out = out;

    void* kargs[] = {(void*)&ma};
    hipError_t e = hipLaunchCooperativeKernel((const void*)main_kernel,
                                              dim3(256), dim3(512), kargs, 0, stream);
    if (e != hipSuccess) {
        (void)hipGetLastError();
        // ---- proven multi-dispatch fallback (round-3 path, ~4.06 ms) ----
        for (int t = 0; t < 49; ++t) {
            StepArgs sa;
            sa.Ain[0] = Ape[t & 1];  sa.Aout[0] = Ape[(t + 1) & 1];
            sa.W[0] = ma.W[0]; sa.bias[0] = biasp; sa.c[0] = c_pe;
            sa.xnext[0] = pose_bf + (size_t)(t + 1) * 75; sa.xstride[0] = 3750;
            sa.Ain[1] = Ave[t & 1];  sa.Aout[1] = Ave[(t + 1) & 1];
            sa.W[1] = ma.W[1]; sa.bias[1] = biasp + 4096; sa.c[1] = c_ve;
            sa.xnext[1] = (t < 48) ? (vel_bf + (size_t)(t + 1) * 75) : nullptr;
            sa.xstride[1] = 3675;
            fb_step_kernel<<<512, 256, 0, stream>>>(sa);
        }
        {
            StepArgs sa;
            sa.Ain[0] = Ape[1]; sa.Aout[0] = Ape[0];
            sa.W[0] = ma.W[0]; sa.bias[0] = biasp; sa.c[0] = c_pe;
            sa.xnext[0] = nullptr; sa.xstride[0] = 3750;
            sa.Ain[1] = sa.Ain[0]; sa.Aout[1] = sa.Aout[0];
            sa.W[1] = sa.W[0]; sa.bias[1] = sa.bias[0]; sa.c[1] = sa.c[0];
            sa.xnext[1] = nullptr; sa.xstride[1] = 3750;
            fb_step_kernel<<<256, 256, 0, stream>>>(sa);
        }
        fb_combine_kernel<<<4096, 256, 0, stream>>>(Ape[0], Ave[1], c_pe, c_ve, Adec[0], c_de);
        for (int d = 0; d < 49; ++d) {
            StepArgs sa;
            sa.Ain[0] = Adec[d & 1]; sa.Aout[0] = Adec[(d + 1) & 1];
            sa.W[0] = ma.W[2]; sa.bias[0] = biasp + 8192; sa.c[0] = c_de;
            sa.xnext[0] = nullptr; sa.xstride[0] = 0;
            sa.Ain[1] = sa.Ain[0]; sa.Aout[1] = sa.Aout[0];
            sa.W[1] = sa.W[0]; sa.bias[1] = sa.bias[0]; sa.c[1] = sa.c[0];
            sa.xnext[1] = nullptr; sa.xstride[1] = 0;
            fb_step_kernel<<<256, 256, 0, stream>>>(sa);
            fb_fc_kernel<<<B_, 128, 0, stream>>>(Adec[(d + 1) & 1], fcWb, fcb, accp, out, d);
        }
    }
}